// Round 14
// baseline (178.146 us; speedup 1.0000x reference)
//
#include <hip/hip_runtime.h>
#include <hip/hip_bf16.h>
#include <cstddef>

#define TT 50
#define NN 512
#define DIN 3
#define HH 128
#define NPG 64
#define DEGCAP 128

typedef short short8 __attribute__((ext_vector_type(8)));
typedef float f32x4 __attribute__((ext_vector_type(4)));

// ---- LDS strides (ushort elems) ----
#define SROW 136
#define VROW 56
#define PROW 72
// attn layout
#define SQ_OFF 0
#define SK_OFF 6800
#define SV_OFF 13600
#define PQ_OFF 20784
#define SMEM_E2 39216      // 78,432 B
// proj layout: bufA @0, bufB @6800 (A-frag rows 50..63 overread bufB: discarded),
//              W fp32 region @15504 (byte 31008), 65,536 B staged via global_load_lds
#define PB_OFF 6800
#define PW_US 15504
#define PW_B 31008
#define SMEM_E1 (PW_US + 32768)   // 96,544 B -> 1 block/CU, 8 waves
// xw2 layout
#define XW_WOFF 17408
#define SMEM_X 34816

static __device__ __forceinline__ unsigned short f2b(float f) {
    unsigned int u = __builtin_bit_cast(unsigned int, f);
    unsigned int r = (u + 0x7fffu + ((u >> 16) & 1u)) >> 16;
    return (unsigned short)r;
}
static __device__ __forceinline__ float b2f(unsigned short h) {
    unsigned int u = ((unsigned int)h) << 16;
    return __builtin_bit_cast(float, u);
}

// Barrier that does NOT drain vmcnt (LDS-only visibility).
static __device__ __forceinline__ void block_sync() {
    __builtin_amdgcn_sched_barrier(0);
    asm volatile("s_waitcnt lgkmcnt(0)");
    __builtin_amdgcn_s_barrier();
    __builtin_amdgcn_sched_barrier(0);
}
static __device__ __forceinline__ void wait_vm0() {
    asm volatile("s_waitcnt vmcnt(0)" ::: "memory");
    __builtin_amdgcn_sched_barrier(0);
}

// asm-pinned global load (attn W_out path, named registers)
#define LD16(dst, addr) \
    asm volatile("global_load_dwordx4 %0, %1, off" : "=&v"(dst) : "v"(addr))

static __device__ __forceinline__ short8 cvt2(float4 a, float4 b) {
    short8 t;
    t[0] = (short)f2b(a.x); t[1] = (short)f2b(a.y);
    t[2] = (short)f2b(a.z); t[3] = (short)f2b(a.w);
    t[4] = (short)f2b(b.x); t[5] = (short)f2b(b.y);
    t[6] = (short)f2b(b.z); t[7] = (short)f2b(b.w);
    return t;
}

typedef __attribute__((address_space(3))) void lds_vt;
typedef __attribute__((address_space(1))) const void gbl_vt;

// Stage a 64 KB fp32 W tile into LDS @PW_B via global_load_lds width=16.
// LDS dest is LINEAR (wave base + lane*16, per HW); global SOURCE is
// XOR-swizzled so that column-major b128 reads are bank-spread (m173/m201).
static __device__ __forceinline__ void stage_w_glds(
    const float* __restrict__ W, unsigned short* sm, int wid, int lane)
{
    const char* src = (const char*)W;
    char* ldsb = (char*)sm + PW_B;
    const int wbase = wid * 8192;
#pragma unroll
    for (int it = 0; it < 8; ++it) {
        const int ub = wbase + it * 1024;        // wave-uniform chunk base
        const int o = ub + (lane << 4);          // this lane's LDS byte
        const int so = o ^ (((o >> 9) & 7) << 4);
        __builtin_amdgcn_global_load_lds((gbl_vt*)(src + so),
                                         (lds_vt*)(ldsb + ub), 16, 0, 0);
    }
}

// Build one wave's 4 B-fragments (col = output row of W) from the swizzled
// fp32 LDS tile, converting to bf16.
static __device__ __forceinline__ void build_bf(const unsigned short* sm,
                                                int col, int g, short8 (&bf)[4])
{
    const char* wb = (const char*)sm + PW_B;
    const int m4 = (col & 7) << 4;
#pragma unroll
    for (int kb = 0; kb < 4; ++kb) {
        const int b = col * 512 + kb * 128 + g * 32;
        float4 u0 = *(const float4*)(wb + (b ^ m4));
        float4 u1 = *(const float4*)(wb + ((b + 16) ^ m4));
        bf[kb] = cvt2(u0, u1);
    }
}

// ---------------------------------------------------------------------------
// A0: ego mask -> MF
// ---------------------------------------------------------------------------
__global__ __launch_bounds__(256) void mf_kernel(
    const int* __restrict__ ego, float* __restrict__ MF)
{
    const int idx = blockIdx.x * 256 + threadIdx.x;
    const int t = idx >> 9;
    const int i = idx & 511;
    const int b = i >> 6, p = i & 63;
    MF[idx] = (ego[b * (TT * NPG) + t * NPG + p] != 0) ? 1.0f : 0.0f;
}

// ---------------------------------------------------------------------------
// A2: edge extraction (row scan + atomic scatter, capped lists)
// ---------------------------------------------------------------------------
__global__ __launch_bounds__(256) void edge_kernel(
    const float* __restrict__ adj, const float* __restrict__ MF,
    int* __restrict__ CNT, unsigned short* __restrict__ IDX)
{
    const int bid = blockIdx.x;        // t*16 + chunk
    const int t = bid >> 4;
    const int r0 = (bid & 15) * 32;
    const int tid = threadIdx.x;

    __shared__ float mfS[NN];
    for (int j = tid; j < NN; j += 256) mfS[j] = MF[t * NN + j];
    __syncthreads();

    const int half = tid >> 7;
    const int l = tid & 127;

    for (int rr = 0; rr < 32; rr += 2) {
        const int i = r0 + rr + half;
        if (mfS[i] == 0.0f) continue;
        const float4 a4 = *reinterpret_cast<const float4*>(
            &adj[(size_t)t * NN * NN + (size_t)i * NN + l * 4]);
        const float av[4] = {a4.x, a4.y, a4.z, a4.w};
        const int jbase = l * 4;
#pragma unroll
        for (int u = 0; u < 4; ++u) {
            const int j = jbase + u;
            if (av[u] != 0.0f && mfS[j] != 0.0f) {
                int pos = atomicAdd(&CNT[t * NN + j], 1);
                if (pos < DEGCAP)   // 13-sigma headroom; dinv uses exact CNT
                    IDX[((size_t)t * NN + j) * DEGCAP + pos] = (unsigned short)i;
            }
        }
    }
}

__global__ __launch_bounds__(256) void dinv_kernel(
    const float* __restrict__ MF, const int* __restrict__ CNT,
    float* __restrict__ DINV)
{
    const int idx = blockIdx.x * 256 + threadIdx.x;
    DINV[idx] = (MF[idx] != 0.0f) ? rsqrtf((float)CNT[idx] + 1.0f) : 0.0f;
}

// ---------------------------------------------------------------------------
// B: XW1 = (x @ W1) * dinv -> bf16
// ---------------------------------------------------------------------------
__global__ __launch_bounds__(256) void xw1_kernel(
    const float* __restrict__ x, const float* __restrict__ W1,
    const float* __restrict__ DINV, unsigned short* __restrict__ XW16)
{
    const int idx = blockIdx.x * 256 + threadIdx.x;
    const int t = idx >> 16;
    const int r = idx & 65535;
    const int i = r >> 7;
    const int f = r & 127;
    const float* xp = x + ((size_t)t * NN + i) * DIN;
    float v = xp[0] * W1[f] + xp[1] * W1[HH + f] + xp[2] * W1[2 * HH + f];
    XW16[idx] = f2b(v * DINV[t * NN + i]);
}

// ---------------------------------------------------------------------------
// C: column aggregation (bf16 in/out, fp32 accum)
// ---------------------------------------------------------------------------
__global__ __launch_bounds__(128) void agg_kernel(
    const unsigned short* __restrict__ XW16, const float* __restrict__ MF,
    const float* __restrict__ DINV, const int* __restrict__ CNT,
    const unsigned short* __restrict__ IDX, const float* __restrict__ bias,
    unsigned short* __restrict__ OUT16, int do_relu)
{
    const int bid = blockIdx.x;
    const int t = bid / NN;
    const int j = bid - t * NN;
    const int f = threadIdx.x;

    __shared__ unsigned short sidx[DEGCAP];

    const float mfj = MF[t * NN + j];
    int cnt = 0;
    if (mfj != 0.0f) cnt = min(CNT[t * NN + j], DEGCAP);
    const unsigned short* lst = IDX + ((size_t)t * NN + j) * DEGCAP;
    for (int k = f; k < cnt; k += 128) sidx[k] = lst[k];
    __syncthreads();

    float outv = 0.0f;
    if (mfj != 0.0f) {
        const unsigned short* base = XW16 + (size_t)t * NN * HH;
        float a0 = b2f(base[j * HH + f]), a1 = 0.0f, a2 = 0.0f, a3 = 0.0f;
        float a4 = 0.0f, a5 = 0.0f, a6 = 0.0f, a7 = 0.0f;
        int k = 0;
        for (; k + 8 <= cnt; k += 8) {
            a0 += b2f(base[(int)sidx[k]     * HH + f]);
            a1 += b2f(base[(int)sidx[k + 1] * HH + f]);
            a2 += b2f(base[(int)sidx[k + 2] * HH + f]);
            a3 += b2f(base[(int)sidx[k + 3] * HH + f]);
            a4 += b2f(base[(int)sidx[k + 4] * HH + f]);
            a5 += b2f(base[(int)sidx[k + 5] * HH + f]);
            a6 += b2f(base[(int)sidx[k + 6] * HH + f]);
            a7 += b2f(base[(int)sidx[k + 7] * HH + f]);
        }
        for (; k + 2 <= cnt; k += 2) {
            a0 += b2f(base[(int)sidx[k]     * HH + f]);
            a1 += b2f(base[(int)sidx[k + 1] * HH + f]);
        }
        if (k < cnt) a2 += b2f(base[(int)sidx[k] * HH + f]);
        outv = DINV[t * NN + j] * (((a0 + a1) + (a2 + a3)) + ((a4 + a5) + (a6 + a7))) + bias[f];
        if (do_relu) outv = fmaxf(outv, 0.0f);
    }
    OUT16[(size_t)t * NN * HH + j * HH + f] = f2b(outv);
}

// ---------------------------------------------------------------------------
// D (MFMA): XW2 = (H @ W2) * dinv on flat [25600][128]
// ---------------------------------------------------------------------------
__global__ __launch_bounds__(256) void xw2_kernel(
    const unsigned short* __restrict__ H16, const float* __restrict__ W2,
    const float* __restrict__ DINV, unsigned short* __restrict__ XW16)
{
    __shared__ unsigned short sm[SMEM_X];
    const int r0 = blockIdx.x * 128;
    const int tid = threadIdx.x;
    const int lane = tid & 63;
    const int wid = tid >> 6;
    const int g = lane >> 4, c = lane & 15;
    const int nt0 = 2 * wid;

#pragma unroll
    for (int it = 0; it < 8; ++it) {
        const int idx = it * 256 + tid;
        const int row = idx >> 4, h8 = (idx & 15) * 8;
        *reinterpret_cast<short8*>(&sm[row * SROW + h8]) =
            *reinterpret_cast<const short8*>(&H16[(size_t)(r0 + row) * HH + h8]);
    }
#pragma unroll
    for (int it = 0; it < 16; ++it) {
        const int flat = it * 1024 + tid * 4;
        float4 w = *reinterpret_cast<const float4*>(W2 + flat);
        const int h = flat >> 7, f0 = flat & 127;
        sm[XW_WOFF + (f0 + 0) * SROW + h] = f2b(w.x);
        sm[XW_WOFF + (f0 + 1) * SROW + h] = f2b(w.y);
        sm[XW_WOFF + (f0 + 2) * SROW + h] = f2b(w.z);
        sm[XW_WOFF + (f0 + 3) * SROW + h] = f2b(w.w);
    }
    __syncthreads();

    f32x4 acc[8][2];
#pragma unroll
    for (int m = 0; m < 8; ++m)
#pragma unroll
        for (int i = 0; i < 2; ++i) acc[m][i] = (f32x4)(0.0f);

#pragma unroll
    for (int kb = 0; kb < 4; ++kb) {
        short8 bf[2];
#pragma unroll
        for (int i = 0; i < 2; ++i)
            bf[i] = *reinterpret_cast<const short8*>(
                &sm[XW_WOFF + (16 * (nt0 + i) + c) * SROW + kb * 32 + 8 * g]);
#pragma unroll
        for (int m = 0; m < 8; ++m) {
            short8 af = *reinterpret_cast<const short8*>(
                &sm[(16 * m + c) * SROW + kb * 32 + 8 * g]);
#pragma unroll
            for (int i = 0; i < 2; ++i)
                acc[m][i] = __builtin_amdgcn_mfma_f32_16x16x32_bf16(af, bf[i], acc[m][i], 0, 0, 0);
        }
    }

#pragma unroll
    for (int m = 0; m < 8; ++m)
#pragma unroll
        for (int r = 0; r < 4; ++r) {
            const int row = 16 * m + 4 * g + r;
            const float dv = DINV[r0 + row];
#pragma unroll
            for (int i = 0; i < 2; ++i)
                XW16[(size_t)(r0 + row) * HH + 16 * (nt0 + i) + c] = f2b(acc[m][i][r] * dv);
        }
}

// ---------------------------------------------------------------------------
// E1: per-(node,s) chained projection pair. W tiles staged via
// global_load_lds (direct TA->LDS fill, no VGPR round-trip), source-XOR-
// swizzled for bank-spread column reads. Wb staged under GEMM1.
// ---------------------------------------------------------------------------
__global__ __launch_bounds__(512, 2) void proj_kernel(
    const unsigned short* __restrict__ EMB16,
    const float* __restrict__ Wq, const float* __restrict__ bq,
    const float* __restrict__ Wk, const float* __restrict__ bk,
    const float* __restrict__ Wv, const float* __restrict__ bv,
    const float* __restrict__ Win, const float* __restrict__ b_in,
    unsigned short* __restrict__ QKVH)
{
    __shared__ unsigned short sm[SMEM_E1];
    const int bid = blockIdx.x;
    const int n = bid / 3;
    const int s = bid - 3 * n;
    const int tid = threadIdx.x;
    const int lane = tid & 63;
    const int wid = tid >> 6;
    const int g = lane >> 4, c = lane & 15;

    const size_t nHH = (size_t)n * HH * HH;
    const size_t n3HH = (size_t)n * 3 * HH * HH;

    const float *Wa, *Wb, *ba, *bb;
    if (s == 0)      { Wa = Wq + nHH; ba = bq + (size_t)n * HH;
                       Wb = Win + n3HH;                 bb = b_in + (size_t)n * 3 * HH; }
    else if (s == 1) { Wa = Wk + nHH; ba = bk + (size_t)n * HH;
                       Wb = Win + n3HH + HH * HH;       bb = b_in + (size_t)n * 3 * HH + HH; }
    else             { Wa = Wv + nHH; ba = bv + (size_t)n * HH;
                       Wb = Win + n3HH + 2 * HH * HH;   bb = b_in + (size_t)n * 3 * HH + 2 * HH; }

    const int col = 16 * wid + c;

    // 1. issue Wa staging (64 KB, direct-to-LDS, flies under emb staging)
    stage_w_glds(Wa, sm, wid, lane);

    const float bav = ba[col];
    const float bbv = bb[col];

    // 2. stage emb (bf16) into bufA
    for (int idx = tid; idx < TT * (HH / 8); idx += 512) {
        int t = idx >> 4, h8 = (idx & 15) * 8;
        *reinterpret_cast<short8*>(&sm[t * SROW + h8]) =
            *reinterpret_cast<const short8*>(&EMB16[((size_t)t * NN + n) * HH + h8]);
    }
    // 3. wait own glds + all waves' fills visible
    wait_vm0();
    block_sync();

    // 4. build GEMM1 B-fragments from the W-LDS tile
    short8 bfA[4];
    build_bf(sm, col, g, bfA);
    // 5. all waves done reading W region before Wb overwrites it
    block_sync();
    // 6. issue Wb staging (flies under GEMM1 + bufB writes)
    stage_w_glds(Wb, sm, wid, lane);

    // 7. GEMM1
    f32x4 acc[4];
#pragma unroll
    for (int m = 0; m < 4; ++m) acc[m] = (f32x4)(0.0f);
#pragma unroll
    for (int kb = 0; kb < 4; ++kb) {
#pragma unroll
        for (int m = 0; m < 4; ++m) {
            short8 af = *reinterpret_cast<const short8*>(
                &sm[(16 * m + c) * SROW + kb * 32 + 8 * g]);
            acc[m] = __builtin_amdgcn_mfma_f32_16x16x32_bf16(af, bfA[kb], acc[m], 0, 0, 0);
        }
    }
    // 8. bufA-region A-frag reads done before bufB writes (regions abut/overlap)
    block_sync();

    // 9. write GEMM1 result -> bufB
#pragma unroll
    for (int m = 0; m < 4; ++m)
#pragma unroll
        for (int r = 0; r < 4; ++r) {
            const int row = 16 * m + 4 * g + r;
            if (row >= TT) continue;
            sm[PB_OFF + row * SROW + col] = f2b(acc[m][r] + bav);
        }
    block_sync();
    // 10. Wb landed (own) + bufB visible; build GEMM2 B-frags
    wait_vm0();
    short8 bfB[4];
    build_bf(sm, col, g, bfB);

    // 11. GEMM2
#pragma unroll
    for (int m = 0; m < 4; ++m) acc[m] = (f32x4)(0.0f);
#pragma unroll
    for (int kb = 0; kb < 4; ++kb) {
#pragma unroll
        for (int m = 0; m < 4; ++m) {
            short8 af = *reinterpret_cast<const short8*>(
                &sm[PB_OFF + (16 * m + c) * SROW + kb * 32 + 8 * g]);
            acc[m] = __builtin_amdgcn_mfma_f32_16x16x32_bf16(af, bfB[kb], acc[m], 0, 0, 0);
        }
    }

    constexpr float scale = 0.17677669529663687f;  // 1/sqrt(32)
    unsigned short* gout = QKVH + (size_t)(n * 3 + s) * (TT * HH);
#pragma unroll
    for (int m = 0; m < 4; ++m)
#pragma unroll
        for (int r = 0; r < 4; ++r) {
            const int row = 16 * m + 4 * g + r;
            if (row >= TT) continue;
            float v = acc[m][r] + bbv;
            if (s == 0) v *= scale;
            gout[row * HH + col] = f2b(v);
        }
}

// ---------------------------------------------------------------------------
// E2: per-node MHA + out_proj (wave = head). Named-register W_out loads
// issued at start, consumed after attention.
// ---------------------------------------------------------------------------
__global__ __launch_bounds__(256, 1) void attn_kernel(
    const unsigned short* __restrict__ QKVH,
    const float* __restrict__ W_out, const float* __restrict__ b_out,
    float* __restrict__ out)
{
    __shared__ unsigned short sm[SMEM_E2];
    const int n = blockIdx.x;
    const int tid = threadIdx.x;
    const int lane = tid & 63;
    const int wid = tid >> 6;
    const int g = lane >> 4, c = lane & 15;
    const int nt0 = 2 * wid;

    const float* Wo = W_out + (size_t)n * HH * HH;
    const float* p0 = Wo + (16 * nt0 + c) * HH + 8 * g;
    const float* p1 = Wo + (16 * nt0 + 16 + c) * HH + 8 * g;
    float4 w0, w1, w2, w3, w4, w5, w6, w7, w8, w9, w10, w11, w12, w13, w14, w15;
    LD16(w0,  p0);        LD16(w1,  p0 + 4);
    LD16(w2,  p0 + 32);   LD16(w3,  p0 + 36);
    LD16(w4,  p0 + 64);   LD16(w5,  p0 + 68);
    LD16(w6,  p0 + 96);   LD16(w7,  p0 + 100);
    LD16(w8,  p1);        LD16(w9,  p1 + 4);
    LD16(w10, p1 + 32);   LD16(w11, p1 + 36);
    LD16(w12, p1 + 64);   LD16(w13, p1 + 68);
    LD16(w14, p1 + 96);   LD16(w15, p1 + 100);

    // zero Svt tail (cols 50..55 each row + pad past row 127)
    for (int idx = tid; idx < HH * 6 + 16; idx += 256) {
        if (idx < HH * 6) {
            int d = idx / 6, cc = idx - d * 6;
            sm[SV_OFF + d * VROW + TT + cc] = 0;
        } else {
            sm[SV_OFF + HH * VROW + (idx - HH * 6)] = 0;
        }
    }

    const unsigned short* q16 = QKVH + (size_t)n * 3 * (TT * HH);
    for (int idx = tid; idx < TT * (HH / 8); idx += 256) {
        int t = idx >> 4, h8 = (idx & 15) * 8;
        *reinterpret_cast<short8*>(&sm[SQ_OFF + t * SROW + h8]) =
            *reinterpret_cast<const short8*>(&q16[t * HH + h8]);
        *reinterpret_cast<short8*>(&sm[SK_OFF + t * SROW + h8]) =
            *reinterpret_cast<const short8*>(&q16[TT * HH + t * HH + h8]);
    }
    for (int idx = tid; idx < TT * (HH / 8); idx += 256) {
        int t = idx >> 4, d8 = (idx & 15) * 8;
        short8 v = *reinterpret_cast<const short8*>(&q16[2 * TT * HH + t * HH + d8]);
#pragma unroll
        for (int u = 0; u < 8; ++u)
            sm[SV_OFF + (d8 + u) * VROW + t] = (unsigned short)v[u];
    }
    block_sync();

    const int hd = wid;

    f32x4 sacc[4][4];
#pragma unroll
    for (int m = 0; m < 4; ++m)
#pragma unroll
        for (int j = 0; j < 4; ++j) sacc[m][j] = (f32x4)(0.0f);

    short8 aq[4], bk8[4];
#pragma unroll
    for (int m = 0; m < 4; ++m)
        aq[m] = *reinterpret_cast<const short8*>(&sm[SQ_OFF + (16 * m + c) * SROW + hd * 32 + 8 * g]);
#pragma unroll
    for (int j = 0; j < 4; ++j)
        bk8[j] = *reinterpret_cast<const short8*>(&sm[SK_OFF + (16 * j + c) * SROW + hd * 32 + 8 * g]);
#pragma unroll
    for (int m = 0; m < 4; ++m)
#pragma unroll
        for (int j = 0; j < 4; ++j)
            sacc[m][j] = __builtin_amdgcn_mfma_f32_16x16x32_bf16(aq[m], bk8[j], sacc[m][j], 0, 0, 0);

    const bool mask3 = (c >= 2);
    unsigned short* Pbase = &sm[PQ_OFF + hd * 64 * PROW];
#pragma unroll
    for (int m = 0; m < 4; ++m)
#pragma unroll
        for (int r = 0; r < 4; ++r) {
            float v0 = sacc[m][0][r], v1 = sacc[m][1][r], v2 = sacc[m][2][r];
            float v3 = mask3 ? -3.0e38f : sacc[m][3][r];
            float mx = fmaxf(fmaxf(v0, v1), fmaxf(v2, v3));
            mx = fmaxf(mx, __shfl_xor(mx, 1, 16));
            mx = fmaxf(mx, __shfl_xor(mx, 2, 16));
            mx = fmaxf(mx, __shfl_xor(mx, 4, 16));
            mx = fmaxf(mx, __shfl_xor(mx, 8, 16));
            float e0 = __expf(v0 - mx), e1 = __expf(v1 - mx), e2 = __expf(v2 - mx);
            float e3 = mask3 ? 0.0f : __expf(v3 - mx);
            float sum_ = e0 + e1 + e2 + e3;
            sum_ += __shfl_xor(sum_, 1, 16);
            sum_ += __shfl_xor(sum_, 2, 16);
            sum_ += __shfl_xor(sum_, 4, 16);
            sum_ += __shfl_xor(sum_, 8, 16);
            float inv = 1.0f / sum_;
            const int q = 16 * m + 4 * g + r;
            unsigned short* pr = Pbase + q * PROW;
            pr[c]      = f2b(e0 * inv);
            pr[16 + c] = f2b(e1 * inv);
            pr[32 + c] = f2b(e2 * inv);
            pr[48 + c] = f2b(e3 * inv);
        }
    block_sync();

    f32x4 pacc[2][4];
#pragma unroll
    for (int mtd = 0; mtd < 2; ++mtd)
#pragma unroll
        for (int ntq = 0; ntq < 4; ++ntq) pacc[mtd][ntq] = (f32x4)(0.0f);

#pragma unroll
    for (int kb = 0; kb < 2; ++kb) {
        short8 av[2], bp[4];
#pragma unroll
        for (int mtd = 0; mtd < 2; ++mtd)
            av[mtd] = *reinterpret_cast<const short8*>(&sm[SV_OFF + (hd * 32 + 16 * mtd + c) * VROW + kb * 32 + 8 * g]);
#pragma unroll
        for (int ntq = 0; ntq < 4; ++ntq)
            bp[ntq] = *reinterpret_cast<const short8*>(&sm[PQ_OFF + hd * 64 * PROW + (16 * ntq + c) * PROW + kb * 32 + 8 * g]);
#pragma unroll
        for (int mtd = 0; mtd < 2; ++mtd)
#pragma unroll
            for (int ntq = 0; ntq < 4; ++ntq)
                pacc[mtd][ntq] = __builtin_amdgcn_mfma_f32_16x16x32_bf16(av[mtd], bp[ntq], pacc[mtd][ntq], 0, 0, 0);
    }

#pragma unroll
    for (int mtd = 0; mtd < 2; ++mtd)
#pragma unroll
        for (int ntq = 0; ntq < 4; ++ntq)
#pragma unroll
            for (int r = 0; r < 4; ++r) {
                const int q = 16 * ntq + c;
                if (q < TT)
                    sm[SQ_OFF + q * SROW + hd * 32 + 16 * mtd + 4 * g + r] = f2b(pacc[mtd][ntq][r]);
            }
    block_sync();

    wait_vm0();
    short8 bfO[2][4];
    bfO[0][0] = cvt2(w0, w1);   bfO[0][1] = cvt2(w2, w3);
    bfO[0][2] = cvt2(w4, w5);   bfO[0][3] = cvt2(w6, w7);
    bfO[1][0] = cvt2(w8, w9);   bfO[1][1] = cvt2(w10, w11);
    bfO[1][2] = cvt2(w12, w13); bfO[1][3] = cvt2(w14, w15);

    f32x4 acc[4][2];
#pragma unroll
    for (int m = 0; m < 4; ++m)
#pragma unroll
        for (int i = 0; i < 2; ++i) acc[m][i] = (f32x4)(0.0f);
#pragma unroll
    for (int kb = 0; kb < 4; ++kb) {
        short8 af[4];
#pragma unroll
        for (int m = 0; m < 4; ++m)
            af[m] = *reinterpret_cast<const short8*>(&sm[SQ_OFF + (16 * m + c) * SROW + kb * 32 + 8 * g]);
#pragma unroll
        for (int m = 0; m < 4; ++m)
#pragma unroll
            for (int i = 0; i < 2; ++i)
                acc[m][i] = __builtin_amdgcn_mfma_f32_16x16x32_bf16(af[m], bfO[i][kb], acc[m][i], 0, 0, 0);
    }

    const float bo0 = b_out[(size_t)n * HH + 16 * nt0 + c];
    const float bo1 = b_out[(size_t)n * HH + 16 * nt0 + 16 + c];
    float* outp = out + (size_t)n * (TT * HH);
#pragma unroll
    for (int m = 0; m < 4; ++m)
#pragma unroll
        for (int i = 0; i < 2; ++i)
#pragma unroll
            for (int r = 0; r < 4; ++r) {
                const int row = 16 * m + 4 * g + r;
                if (row >= TT) continue;
                outp[row * HH + 16 * (nt0 + i) + c] = acc[m][i][r] + (i ? bo1 : bo0);
            }
}

// ---------------------------------------------------------------------------
extern "C" void kernel_launch(void* const* d_in, const int* in_sizes, int n_in,
                              void* d_out, int out_size, void* d_ws, size_t ws_size,
                              hipStream_t stream)
{
    const float* x     = (const float*)d_in[0];
    const float* adj   = (const float*)d_in[1];
    const int*   ego   = (const int*)d_in[2];
    const float* W1    = (const float*)d_in[3];
    const float* b1    = (const float*)d_in[4];
    const float* W2    = (const float*)d_in[5];
    const float* b2    = (const float*)d_in[6];
    const float* Wq    = (const float*)d_in[7];
    const float* bq    = (const float*)d_in[8];
    const float* Wk    = (const float*)d_in[9];
    const float* bk    = (const float*)d_in[10];
    const float* Wv    = (const float*)d_in[11];
    const float* bv    = (const float*)d_in[12];
    const float* W_in  = (const float*)d_in[13];
    const float* b_in  = (const float*)d_in[14];
    const float* W_out = (const float*)d_in[15];
    const float* b_out = (const float*)d_in[16];
    float* out = (float*)d_out;

    char* ws = (char*)d_ws;
    float*          MF    = (float*)(ws + 0);
    float*          DINV  = (float*)(ws + 102400);
    int*            CNT   = (int*)(ws + 204800);
    unsigned short* IDX   = (unsigned short*)(ws + 307200);     // 6,553,600
    unsigned short* XW16  = (unsigned short*)(ws + 6860800);    // 6,553,600
    unsigned short* H16   = (unsigned short*)(ws + 13414400);   // 6,553,600
    unsigned short* EMB16 = (unsigned short*)(ws + 19968000);   // 6,553,600
    unsigned short* QKVH  = (unsigned short*)(ws + 26521600);   // 19,660,800

    hipMemsetAsync(CNT, 0, TT * NN * sizeof(int), stream);
    mf_kernel<<<dim3(100), dim3(256), 0, stream>>>(ego, MF);
    edge_kernel<<<dim3(TT * 16), dim3(256), 0, stream>>>(adj, MF, CNT, IDX);
    dinv_kernel<<<dim3(100), dim3(256), 0, stream>>>(MF, CNT, DINV);
    xw1_kernel<<<dim3(12800), dim3(256), 0, stream>>>(x, W1, DINV, XW16);
    agg_kernel<<<dim3(TT * NN), dim3(128), 0, stream>>>(XW16, MF, DINV, CNT, IDX, b1, H16, 1);
    xw2_kernel<<<dim3(200), dim3(256), 0, stream>>>(H16, W2, DINV, XW16);
    agg_kernel<<<dim3(TT * NN), dim3(128), 0, stream>>>(XW16, MF, DINV, CNT, IDX, b2, EMB16, 0);
    proj_kernel<<<dim3(NN * 3), dim3(512), 0, stream>>>(EMB16, Wq, bq, Wk, bk, Wv, bv,
                                                        W_in, b_in, QKVH);
    attn_kernel<<<dim3(NN), dim3(256), 0, stream>>>(QKVH, W_out, b_out, out);
}

// Round 15
// 160.232 us; speedup vs baseline: 1.1118x; 1.1118x over previous
//
#include <hip/hip_runtime.h>
#include <hip/hip_bf16.h>
#include <cstddef>

#define TT 50
#define NN 512
#define DIN 3
#define HH 128
#define NPG 64
#define DEGCAP 128

typedef short short8 __attribute__((ext_vector_type(8)));
typedef float f32x4 __attribute__((ext_vector_type(4)));

// ---- LDS strides (ushort elems) ----
#define SROW 136
#define VROW 56
#define PROW 72
// fused node_attn layout
#define SQ_OFF 0
#define SK_OFF 6800
#define SV_OFF 13600          // 7184 elems (128*56 + 16 tail)
#define PQ_OFF 20784          // emb first, then P (4*64*72=18432)
#define SMEM_NA 39216         // 78,432 B -> 2 blocks/CU
// xw2 layout
#define XW_WOFF 17408
#define SMEM_X 34816

static __device__ __forceinline__ unsigned short f2b(float f) {
    unsigned int u = __builtin_bit_cast(unsigned int, f);
    unsigned int r = (u + 0x7fffu + ((u >> 16) & 1u)) >> 16;
    return (unsigned short)r;
}
static __device__ __forceinline__ float b2f(unsigned short h) {
    unsigned int u = ((unsigned int)h) << 16;
    return __builtin_bit_cast(float, u);
}

// Barrier that does NOT drain vmcnt (LDS-only visibility).
static __device__ __forceinline__ void block_sync() {
    __builtin_amdgcn_sched_barrier(0);
    asm volatile("s_waitcnt lgkmcnt(0)");
    __builtin_amdgcn_s_barrier();
    __builtin_amdgcn_sched_barrier(0);
}

static __device__ __forceinline__ short8 cvt2(float4 a, float4 b) {
    short8 t;
    t[0] = (short)f2b(a.x); t[1] = (short)f2b(a.y);
    t[2] = (short)f2b(a.z); t[3] = (short)f2b(a.w);
    t[4] = (short)f2b(b.x); t[5] = (short)f2b(b.y);
    t[6] = (short)f2b(b.z); t[7] = (short)f2b(b.w);
    return t;
}

// ---------------------------------------------------------------------------
// A0: ego mask -> MF
// ---------------------------------------------------------------------------
__global__ __launch_bounds__(256) void mf_kernel(
    const int* __restrict__ ego, float* __restrict__ MF)
{
    const int idx = blockIdx.x * 256 + threadIdx.x;
    const int t = idx >> 9;
    const int i = idx & 511;
    const int b = i >> 6, p = i & 63;
    MF[idx] = (ego[b * (TT * NPG) + t * NPG + p] != 0) ? 1.0f : 0.0f;
}

// ---------------------------------------------------------------------------
// A2: edge extraction (row scan + atomic scatter, capped lists)
// ---------------------------------------------------------------------------
__global__ __launch_bounds__(256) void edge_kernel(
    const float* __restrict__ adj, const float* __restrict__ MF,
    int* __restrict__ CNT, unsigned short* __restrict__ IDX)
{
    const int bid = blockIdx.x;        // t*16 + chunk
    const int t = bid >> 4;
    const int r0 = (bid & 15) * 32;
    const int tid = threadIdx.x;

    __shared__ float mfS[NN];
    for (int j = tid; j < NN; j += 256) mfS[j] = MF[t * NN + j];
    __syncthreads();

    const int half = tid >> 7;
    const int l = tid & 127;

    for (int rr = 0; rr < 32; rr += 2) {
        const int i = r0 + rr + half;
        if (mfS[i] == 0.0f) continue;
        const float4 a4 = *reinterpret_cast<const float4*>(
            &adj[(size_t)t * NN * NN + (size_t)i * NN + l * 4]);
        const float av[4] = {a4.x, a4.y, a4.z, a4.w};
        const int jbase = l * 4;
#pragma unroll
        for (int u = 0; u < 4; ++u) {
            const int j = jbase + u;
            if (av[u] != 0.0f && mfS[j] != 0.0f) {
                int pos = atomicAdd(&CNT[t * NN + j], 1);
                if (pos < DEGCAP)   // 13-sigma headroom; dinv uses exact CNT
                    IDX[((size_t)t * NN + j) * DEGCAP + pos] = (unsigned short)i;
            }
        }
    }
}

__global__ __launch_bounds__(256) void dinv_kernel(
    const float* __restrict__ MF, const int* __restrict__ CNT,
    float* __restrict__ DINV)
{
    const int idx = blockIdx.x * 256 + threadIdx.x;
    DINV[idx] = (MF[idx] != 0.0f) ? rsqrtf((float)CNT[idx] + 1.0f) : 0.0f;
}

// ---------------------------------------------------------------------------
// B: XW1 = (x @ W1) * dinv -> bf16
// ---------------------------------------------------------------------------
__global__ __launch_bounds__(256) void xw1_kernel(
    const float* __restrict__ x, const float* __restrict__ W1,
    const float* __restrict__ DINV, unsigned short* __restrict__ XW16)
{
    const int idx = blockIdx.x * 256 + threadIdx.x;
    const int t = idx >> 16;
    const int r = idx & 65535;
    const int i = r >> 7;
    const int f = r & 127;
    const float* xp = x + ((size_t)t * NN + i) * DIN;
    float v = xp[0] * W1[f] + xp[1] * W1[HH + f] + xp[2] * W1[2 * HH + f];
    XW16[idx] = f2b(v * DINV[t * NN + i]);
}

// ---------------------------------------------------------------------------
// C: column aggregation (bf16 in/out, fp32 accum)
// ---------------------------------------------------------------------------
__global__ __launch_bounds__(128) void agg_kernel(
    const unsigned short* __restrict__ XW16, const float* __restrict__ MF,
    const float* __restrict__ DINV, const int* __restrict__ CNT,
    const unsigned short* __restrict__ IDX, const float* __restrict__ bias,
    unsigned short* __restrict__ OUT16, int do_relu)
{
    const int bid = blockIdx.x;
    const int t = bid / NN;
    const int j = bid - t * NN;
    const int f = threadIdx.x;

    __shared__ unsigned short sidx[DEGCAP];

    const float mfj = MF[t * NN + j];
    int cnt = 0;
    if (mfj != 0.0f) cnt = min(CNT[t * NN + j], DEGCAP);
    const unsigned short* lst = IDX + ((size_t)t * NN + j) * DEGCAP;
    for (int k = f; k < cnt; k += 128) sidx[k] = lst[k];
    __syncthreads();

    float outv = 0.0f;
    if (mfj != 0.0f) {
        const unsigned short* base = XW16 + (size_t)t * NN * HH;
        float a0 = b2f(base[j * HH + f]), a1 = 0.0f, a2 = 0.0f, a3 = 0.0f;
        float a4 = 0.0f, a5 = 0.0f, a6 = 0.0f, a7 = 0.0f;
        int k = 0;
        for (; k + 8 <= cnt; k += 8) {
            a0 += b2f(base[(int)sidx[k]     * HH + f]);
            a1 += b2f(base[(int)sidx[k + 1] * HH + f]);
            a2 += b2f(base[(int)sidx[k + 2] * HH + f]);
            a3 += b2f(base[(int)sidx[k + 3] * HH + f]);
            a4 += b2f(base[(int)sidx[k + 4] * HH + f]);
            a5 += b2f(base[(int)sidx[k + 5] * HH + f]);
            a6 += b2f(base[(int)sidx[k + 6] * HH + f]);
            a7 += b2f(base[(int)sidx[k + 7] * HH + f]);
        }
        for (; k + 2 <= cnt; k += 2) {
            a0 += b2f(base[(int)sidx[k]     * HH + f]);
            a1 += b2f(base[(int)sidx[k + 1] * HH + f]);
        }
        if (k < cnt) a2 += b2f(base[(int)sidx[k] * HH + f]);
        outv = DINV[t * NN + j] * (((a0 + a1) + (a2 + a3)) + ((a4 + a5) + (a6 + a7))) + bias[f];
        if (do_relu) outv = fmaxf(outv, 0.0f);
    }
    OUT16[(size_t)t * NN * HH + j * HH + f] = f2b(outv);
}

// ---------------------------------------------------------------------------
// D (MFMA): XW2 = (H @ W2) * dinv on flat [25600][128]
// ---------------------------------------------------------------------------
__global__ __launch_bounds__(256) void xw2_kernel(
    const unsigned short* __restrict__ H16, const float* __restrict__ W2,
    const float* __restrict__ DINV, unsigned short* __restrict__ XW16)
{
    __shared__ unsigned short sm[SMEM_X];
    const int r0 = blockIdx.x * 128;
    const int tid = threadIdx.x;
    const int lane = tid & 63;
    const int wid = tid >> 6;
    const int g = lane >> 4, c = lane & 15;
    const int nt0 = 2 * wid;

#pragma unroll
    for (int it = 0; it < 8; ++it) {
        const int idx = it * 256 + tid;
        const int row = idx >> 4, h8 = (idx & 15) * 8;
        *reinterpret_cast<short8*>(&sm[row * SROW + h8]) =
            *reinterpret_cast<const short8*>(&H16[(size_t)(r0 + row) * HH + h8]);
    }
#pragma unroll
    for (int it = 0; it < 16; ++it) {
        const int flat = it * 1024 + tid * 4;
        float4 w = *reinterpret_cast<const float4*>(W2 + flat);
        const int h = flat >> 7, f0 = flat & 127;
        sm[XW_WOFF + (f0 + 0) * SROW + h] = f2b(w.x);
        sm[XW_WOFF + (f0 + 1) * SROW + h] = f2b(w.y);
        sm[XW_WOFF + (f0 + 2) * SROW + h] = f2b(w.z);
        sm[XW_WOFF + (f0 + 3) * SROW + h] = f2b(w.w);
    }
    __syncthreads();

    f32x4 acc[8][2];
#pragma unroll
    for (int m = 0; m < 8; ++m)
#pragma unroll
        for (int i = 0; i < 2; ++i) acc[m][i] = (f32x4)(0.0f);

#pragma unroll
    for (int kb = 0; kb < 4; ++kb) {
        short8 bf[2];
#pragma unroll
        for (int i = 0; i < 2; ++i)
            bf[i] = *reinterpret_cast<const short8*>(
                &sm[XW_WOFF + (16 * (nt0 + i) + c) * SROW + kb * 32 + 8 * g]);
#pragma unroll
        for (int m = 0; m < 8; ++m) {
            short8 af = *reinterpret_cast<const short8*>(
                &sm[(16 * m + c) * SROW + kb * 32 + 8 * g]);
#pragma unroll
            for (int i = 0; i < 2; ++i)
                acc[m][i] = __builtin_amdgcn_mfma_f32_16x16x32_bf16(af, bf[i], acc[m][i], 0, 0, 0);
        }
    }

#pragma unroll
    for (int m = 0; m < 8; ++m)
#pragma unroll
        for (int r = 0; r < 4; ++r) {
            const int row = 16 * m + 4 * g + r;
            const float dv = DINV[r0 + row];
#pragma unroll
            for (int i = 0; i < 2; ++i)
                XW16[(size_t)(r0 + row) * HH + 16 * (nt0 + i) + c] = f2b(acc[m][i][r] * dv);
        }
}

// ---------------------------------------------------------------------------
// Kernel E (fused): per-node 7-GEMM chain + MHA. 1 block = 1 node, 4 waves.
// Wave w owns output cols [32w, 32w+32) in stage GEMMs, head w in attention.
// R3-proven structure; QKVH round-trip eliminated.
// MODE: 0 = LDS store (SROW); 1 = +1/sqrt(32); 2 = transposed store (VROW);
//       3 = fp32 global store.
// ---------------------------------------------------------------------------
template<int MODE>
__device__ __forceinline__ void stage(
    unsigned short* __restrict__ sm, int in_off, int out_off,
    const float* __restrict__ W, const float* __restrict__ bias,
    float* __restrict__ gout)
{
    const int tid = threadIdx.x;
    const int lane = tid & 63;
    const int wid = tid >> 6;
    const int g = lane >> 4, c = lane & 15;
    const int nt0 = 2 * wid;

    const float bv0 = bias[16 * nt0 + c];
    const float bv1 = bias[16 * nt0 + 16 + c];

    short8 bf[2][4];
#pragma unroll
    for (int i = 0; i < 2; ++i) {
        const float* wr = W + (16 * (nt0 + i) + c) * HH + 8 * g;
#pragma unroll
        for (int kb = 0; kb < 4; ++kb) {
            float4 w0 = *reinterpret_cast<const float4*>(wr + kb * 32);
            float4 w1 = *reinterpret_cast<const float4*>(wr + kb * 32 + 4);
            bf[i][kb] = cvt2(w0, w1);
        }
    }

    f32x4 acc[4][2];
#pragma unroll
    for (int m = 0; m < 4; ++m)
#pragma unroll
        for (int i = 0; i < 2; ++i) acc[m][i] = (f32x4)(0.0f);

#pragma unroll
    for (int kb = 0; kb < 4; ++kb) {
        short8 af[4];
#pragma unroll
        for (int m = 0; m < 4; ++m)
            af[m] = *reinterpret_cast<const short8*>(
                &sm[in_off + (16 * m + c) * SROW + kb * 32 + 8 * g]);
#pragma unroll
        for (int m = 0; m < 4; ++m)
#pragma unroll
            for (int i = 0; i < 2; ++i)
                acc[m][i] = __builtin_amdgcn_mfma_f32_16x16x32_bf16(af[m], bf[i][kb], acc[m][i], 0, 0, 0);
    }
    block_sync();   // all reads of in_off done (in-place safe)

    constexpr float scale = 0.17677669529663687f;  // 1/sqrt(32)
#pragma unroll
    for (int m = 0; m < 4; ++m)
#pragma unroll
        for (int i = 0; i < 2; ++i)
#pragma unroll
            for (int r = 0; r < 4; ++r) {
                const int row = 16 * m + 4 * g + r;
                if (row >= TT) continue;
                float v = acc[m][i][r] + (i ? bv1 : bv0);
                if (MODE == 1) v *= scale;
                const int col = 16 * (nt0 + i) + c;
                if (MODE == 3)      gout[row * HH + col] = v;
                else if (MODE == 2) sm[out_off + col * VROW + row] = f2b(v);
                else                sm[out_off + row * SROW + col] = f2b(v);
            }
    block_sync();
}

__global__ __launch_bounds__(256) void node_attn_kernel(
    const unsigned short* __restrict__ EMB16,
    const float* __restrict__ Wq, const float* __restrict__ bq,
    const float* __restrict__ Wk, const float* __restrict__ bk,
    const float* __restrict__ Wv, const float* __restrict__ bv,
    const float* __restrict__ W_in, const float* __restrict__ b_in,
    const float* __restrict__ W_out, const float* __restrict__ b_out,
    float* __restrict__ out)
{
    __shared__ unsigned short sm[SMEM_NA];
    const int n = blockIdx.x;
    const int tid = threadIdx.x;
    const int lane = tid & 63;
    const int wid = tid >> 6;
    const int g = lane >> 4, c = lane & 15;

    // zero Svt tail: cols 50..55 each d-row + 16-elem pad past row 127
    // (keeps PV A-frag reads finite; P's j>=50 zeros do the masking)
    for (int idx = tid; idx < HH * 6 + 16; idx += 256) {
        if (idx < HH * 6) {
            int d = idx / 6, cc = idx - d * 6;
            sm[SV_OFF + d * VROW + TT + cc] = 0;
        } else {
            sm[SV_OFF + HH * VROW + (idx - HH * 6)] = 0;
        }
    }

    // stage emb (bf16) into PQ region
    for (int idx = tid; idx < TT * (HH / 8); idx += 256) {
        int t = idx >> 4, h8 = (idx & 15) * 8;
        *reinterpret_cast<short8*>(&sm[PQ_OFF + t * SROW + h8]) =
            *reinterpret_cast<const short8*>(&EMB16[((size_t)t * NN + n) * HH + h8]);
    }
    block_sync();

    const size_t nHH = (size_t)n * HH * HH;
    const size_t n3HH = (size_t)n * 3 * HH * HH;

    // q/k/v projections (read emb @ PQ)
    stage<0>(sm, PQ_OFF, SQ_OFF, Wq + nHH, bq + (size_t)n * HH, nullptr);
    stage<0>(sm, PQ_OFF, SK_OFF, Wk + nHH, bk + (size_t)n * HH, nullptr);
    stage<0>(sm, PQ_OFF, SV_OFF, Wv + nHH, bv + (size_t)n * HH, nullptr);
    // in_proj: qh (scaled, in-place), kh (in-place), vh (transposed)
    stage<1>(sm, SQ_OFF, SQ_OFF, W_in + n3HH,                b_in + (size_t)n * 3 * HH,          nullptr);
    stage<0>(sm, SK_OFF, SK_OFF, W_in + n3HH + HH * HH,      b_in + (size_t)n * 3 * HH + HH,     nullptr);
    stage<2>(sm, SV_OFF, SV_OFF, W_in + n3HH + 2 * HH * HH,  b_in + (size_t)n * 3 * HH + 2 * HH, nullptr);

    // ---- attention: wave = head ----
    const int hd = wid;

    f32x4 sacc[4][4];
#pragma unroll
    for (int m = 0; m < 4; ++m)
#pragma unroll
        for (int j = 0; j < 4; ++j) sacc[m][j] = (f32x4)(0.0f);

    short8 aq[4], bk8[4];
#pragma unroll
    for (int m = 0; m < 4; ++m)
        aq[m] = *reinterpret_cast<const short8*>(&sm[SQ_OFF + (16 * m + c) * SROW + hd * 32 + 8 * g]);
#pragma unroll
    for (int j = 0; j < 4; ++j)
        bk8[j] = *reinterpret_cast<const short8*>(&sm[SK_OFF + (16 * j + c) * SROW + hd * 32 + 8 * g]);
#pragma unroll
    for (int m = 0; m < 4; ++m)
#pragma unroll
        for (int j = 0; j < 4; ++j)
            sacc[m][j] = __builtin_amdgcn_mfma_f32_16x16x32_bf16(aq[m], bk8[j], sacc[m][j], 0, 0, 0);

    const bool mask3 = (c >= 2);
    unsigned short* Pbase = &sm[PQ_OFF + hd * 64 * PROW];
#pragma unroll
    for (int m = 0; m < 4; ++m)
#pragma unroll
        for (int r = 0; r < 4; ++r) {
            float v0 = sacc[m][0][r], v1 = sacc[m][1][r], v2 = sacc[m][2][r];
            float v3 = mask3 ? -3.0e38f : sacc[m][3][r];
            float mx = fmaxf(fmaxf(v0, v1), fmaxf(v2, v3));
            mx = fmaxf(mx, __shfl_xor(mx, 1, 16));
            mx = fmaxf(mx, __shfl_xor(mx, 2, 16));
            mx = fmaxf(mx, __shfl_xor(mx, 4, 16));
            mx = fmaxf(mx, __shfl_xor(mx, 8, 16));
            float e0 = __expf(v0 - mx), e1 = __expf(v1 - mx), e2 = __expf(v2 - mx);
            float e3 = mask3 ? 0.0f : __expf(v3 - mx);
            float sum_ = e0 + e1 + e2 + e3;
            sum_ += __shfl_xor(sum_, 1, 16);
            sum_ += __shfl_xor(sum_, 2, 16);
            sum_ += __shfl_xor(sum_, 4, 16);
            sum_ += __shfl_xor(sum_, 8, 16);
            float inv = 1.0f / sum_;
            const int q = 16 * m + 4 * g + r;
            unsigned short* pr = Pbase + q * PROW;
            pr[c]      = f2b(e0 * inv);
            pr[16 + c] = f2b(e1 * inv);
            pr[32 + c] = f2b(e2 * inv);
            pr[48 + c] = f2b(e3 * inv);
        }
    block_sync();   // P visible; all QK^T reads of SQ done

    f32x4 pacc[2][4];
#pragma unroll
    for (int mtd = 0; mtd < 2; ++mtd)
#pragma unroll
        for (int ntq = 0; ntq < 4; ++ntq) pacc[mtd][ntq] = (f32x4)(0.0f);

#pragma unroll
    for (int kb = 0; kb < 2; ++kb) {
        short8 av[2], bp[4];
#pragma unroll
        for (int mtd = 0; mtd < 2; ++mtd)
            av[mtd] = *reinterpret_cast<const short8*>(&sm[SV_OFF + (hd * 32 + 16 * mtd + c) * VROW + kb * 32 + 8 * g]);
#pragma unroll
        for (int ntq = 0; ntq < 4; ++ntq)
            bp[ntq] = *reinterpret_cast<const short8*>(&sm[PQ_OFF + hd * 64 * PROW + (16 * ntq + c) * PROW + kb * 32 + 8 * g]);
#pragma unroll
        for (int mtd = 0; mtd < 2; ++mtd)
#pragma unroll
            for (int ntq = 0; ntq < 4; ++ntq)
                pacc[mtd][ntq] = __builtin_amdgcn_mfma_f32_16x16x32_bf16(av[mtd], bp[ntq], pacc[mtd][ntq], 0, 0, 0);
    }

    // O -> SQ region (dead)
#pragma unroll
    for (int mtd = 0; mtd < 2; ++mtd)
#pragma unroll
        for (int ntq = 0; ntq < 4; ++ntq)
#pragma unroll
            for (int r = 0; r < 4; ++r) {
                const int q = 16 * ntq + c;
                if (q < TT)
                    sm[SQ_OFF + q * SROW + hd * 32 + 16 * mtd + 4 * g + r] = f2b(pacc[mtd][ntq][r]);
            }
    block_sync();

    // out_proj -> global fp32
    stage<3>(sm, SQ_OFF, 0, W_out + nHH, b_out + (size_t)n * HH, out + (size_t)n * TT * HH);
}

// ---------------------------------------------------------------------------
extern "C" void kernel_launch(void* const* d_in, const int* in_sizes, int n_in,
                              void* d_out, int out_size, void* d_ws, size_t ws_size,
                              hipStream_t stream)
{
    const float* x     = (const float*)d_in[0];
    const float* adj   = (const float*)d_in[1];
    const int*   ego   = (const int*)d_in[2];
    const float* W1    = (const float*)d_in[3];
    const float* b1    = (const float*)d_in[4];
    const float* W2    = (const float*)d_in[5];
    const float* b2    = (const float*)d_in[6];
    const float* Wq    = (const float*)d_in[7];
    const float* bq    = (const float*)d_in[8];
    const float* Wk    = (const float*)d_in[9];
    const float* bk    = (const float*)d_in[10];
    const float* Wv    = (const float*)d_in[11];
    const float* bv    = (const float*)d_in[12];
    const float* W_in  = (const float*)d_in[13];
    const float* b_in  = (const float*)d_in[14];
    const float* W_out = (const float*)d_in[15];
    const float* b_out = (const float*)d_in[16];
    float* out = (float*)d_out;

    char* ws = (char*)d_ws;
    float*          MF    = (float*)(ws + 0);
    float*          DINV  = (float*)(ws + 102400);
    int*            CNT   = (int*)(ws + 204800);
    unsigned short* IDX   = (unsigned short*)(ws + 307200);     // 6,553,600
    unsigned short* XW16  = (unsigned short*)(ws + 6860800);    // 6,553,600
    unsigned short* H16   = (unsigned short*)(ws + 13414400);   // 6,553,600
    unsigned short* EMB16 = (unsigned short*)(ws + 19968000);   // 6,553,600

    hipMemsetAsync(CNT, 0, TT * NN * sizeof(int), stream);
    mf_kernel<<<dim3(100), dim3(256), 0, stream>>>(ego, MF);
    edge_kernel<<<dim3(TT * 16), dim3(256), 0, stream>>>(adj, MF, CNT, IDX);
    dinv_kernel<<<dim3(100), dim3(256), 0, stream>>>(MF, CNT, DINV);
    xw1_kernel<<<dim3(12800), dim3(256), 0, stream>>>(x, W1, DINV, XW16);
    agg_kernel<<<dim3(TT * NN), dim3(128), 0, stream>>>(XW16, MF, DINV, CNT, IDX, b1, H16, 1);
    xw2_kernel<<<dim3(200), dim3(256), 0, stream>>>(H16, W2, DINV, XW16);
    agg_kernel<<<dim3(TT * NN), dim3(128), 0, stream>>>(XW16, MF, DINV, CNT, IDX, b2, EMB16, 0);
    node_attn_kernel<<<dim3(NN), dim3(256), 0, stream>>>(EMB16, Wq, bq, Wk, bk, Wv, bv,
                                                         W_in, b_in, W_out, b_out, out);
}

// Round 16
// 139.003 us; speedup vs baseline: 1.2816x; 1.1527x over previous
//
#include <hip/hip_runtime.h>
#include <hip/hip_bf16.h>
#include <cstddef>

#define TT 50
#define NN 512
#define DIN 3
#define HH 128
#define NPG 64
#define DEGCAP 128

typedef short short8 __attribute__((ext_vector_type(8)));
typedef float f32x4 __attribute__((ext_vector_type(4)));

// ---- LDS strides (ushort elems) ----
#define SROW 136
#define VROW 56
#define PROW 72
// fused node_attn layout
#define SQ_OFF 0
#define SK_OFF 6800
#define SV_OFF 13600          // 7184 elems (128*56 + 16 tail)
#define PQ_OFF 20784          // emb first, then P (4*64*72=18432)
#define SMEM_NA 39216         // 78,432 B -> 2 blocks/CU
// xw2 layout
#define XW_WOFF 17408
#define SMEM_X 34816

static __device__ __forceinline__ unsigned short f2b(float f) {
    unsigned int u = __builtin_bit_cast(unsigned int, f);
    unsigned int r = (u + 0x7fffu + ((u >> 16) & 1u)) >> 16;
    return (unsigned short)r;
}
static __device__ __forceinline__ float b2f(unsigned short h) {
    unsigned int u = ((unsigned int)h) << 16;
    return __builtin_bit_cast(float, u);
}

// Barrier that does NOT drain vmcnt (LDS-only visibility).
static __device__ __forceinline__ void block_sync() {
    __builtin_amdgcn_sched_barrier(0);
    asm volatile("s_waitcnt lgkmcnt(0)");
    __builtin_amdgcn_s_barrier();
    __builtin_amdgcn_sched_barrier(0);
}

static __device__ __forceinline__ short8 cvt2(float4 a, float4 b) {
    short8 t;
    t[0] = (short)f2b(a.x); t[1] = (short)f2b(a.y);
    t[2] = (short)f2b(a.z); t[3] = (short)f2b(a.w);
    t[4] = (short)f2b(b.x); t[5] = (short)f2b(b.y);
    t[6] = (short)f2b(b.z); t[7] = (short)f2b(b.w);
    return t;
}

// ---------------------------------------------------------------------------
// A0: ego mask -> MF ; also zeroes CNT (replaces memset dispatch)
// ---------------------------------------------------------------------------
__global__ __launch_bounds__(256) void mf_kernel(
    const int* __restrict__ ego, float* __restrict__ MF, int* __restrict__ CNT)
{
    const int idx = blockIdx.x * 256 + threadIdx.x;
    const int t = idx >> 9;
    const int i = idx & 511;
    const int b = i >> 6, p = i & 63;
    MF[idx] = (ego[b * (TT * NPG) + t * NPG + p] != 0) ? 1.0f : 0.0f;
    CNT[idx] = 0;
}

// ---------------------------------------------------------------------------
// A2: edge extraction (row scan + atomic scatter, capped lists)
// 1600 blocks (16 rows each), 256 threads processing 2 rows at a time.
// ---------------------------------------------------------------------------
__global__ __launch_bounds__(256) void edge_kernel(
    const float* __restrict__ adj, const float* __restrict__ MF,
    int* __restrict__ CNT, unsigned short* __restrict__ IDX)
{
    const int bid = blockIdx.x;        // t*32 + chunk
    const int t = bid >> 5;
    const int r0 = (bid & 31) * 16;
    const int tid = threadIdx.x;

    __shared__ float mfS[NN];
    for (int j = tid; j < NN; j += 256) mfS[j] = MF[t * NN + j];
    __syncthreads();

    const int half = tid >> 7;
    const int l = tid & 127;

    for (int rr = 0; rr < 16; rr += 2) {
        const int i = r0 + rr + half;
        if (mfS[i] == 0.0f) continue;
        const float4 a4 = *reinterpret_cast<const float4*>(
            &adj[(size_t)t * NN * NN + (size_t)i * NN + l * 4]);
        const float av[4] = {a4.x, a4.y, a4.z, a4.w};
        const int jbase = l * 4;
#pragma unroll
        for (int u = 0; u < 4; ++u) {
            const int j = jbase + u;
            if (av[u] != 0.0f && mfS[j] != 0.0f) {
                int pos = atomicAdd(&CNT[t * NN + j], 1);
                if (pos < DEGCAP)   // 13-sigma headroom; dinv uses exact CNT
                    IDX[((size_t)t * NN + j) * DEGCAP + pos] = (unsigned short)i;
            }
        }
    }
}

__global__ __launch_bounds__(256) void dinv_kernel(
    const float* __restrict__ MF, const int* __restrict__ CNT,
    float* __restrict__ DINV)
{
    const int idx = blockIdx.x * 256 + threadIdx.x;
    DINV[idx] = (MF[idx] != 0.0f) ? rsqrtf((float)CNT[idx] + 1.0f) : 0.0f;
}

// ---------------------------------------------------------------------------
// C1 (fused xw1+agg1): per-(t,j) gather with on-the-fly (x @ W1)*dinv.
// W1 (3x128) LDS-resident; each neighbor costs 4 broadcast loads + 3 FMA.
// out = relu( dinv_j * sum_i (x_i @ W1)*dinv_i + b1 )   (i = self + in-list)
// ---------------------------------------------------------------------------
__global__ __launch_bounds__(128) void agg1_kernel(
    const float* __restrict__ x, const float* __restrict__ W1,
    const float* __restrict__ MF, const float* __restrict__ DINV,
    const int* __restrict__ CNT, const unsigned short* __restrict__ IDX,
    const float* __restrict__ b1, unsigned short* __restrict__ H16)
{
    const int bid = blockIdx.x;
    const int t = bid / NN;
    const int j = bid - t * NN;
    const int f = threadIdx.x;

    __shared__ float W1S[3 * HH];
    __shared__ unsigned short sidx[DEGCAP];

    W1S[f] = W1[f];
    W1S[HH + f] = W1[HH + f];
    W1S[2 * HH + f] = W1[2 * HH + f];

    const float mfj = MF[t * NN + j];
    int cnt = 0;
    if (mfj != 0.0f) cnt = min(CNT[t * NN + j], DEGCAP);
    const unsigned short* lst = IDX + ((size_t)t * NN + j) * DEGCAP;
    if (f < cnt) sidx[f] = lst[f];
    __syncthreads();

    float outv = 0.0f;
    if (mfj != 0.0f) {
        const float* xt = x + (size_t)t * NN * DIN;
        const float* dv = DINV + t * NN;
        const float w0 = W1S[f], w1 = W1S[HH + f], w2 = W1S[2 * HH + f];

        // self term
        float a0 = (xt[j * 3] * w0 + xt[j * 3 + 1] * w1 + xt[j * 3 + 2] * w2) * dv[j];
        float a1 = 0.0f, a2 = 0.0f, a3 = 0.0f;
        int k = 0;
        for (; k + 4 <= cnt; k += 4) {
            const int i0 = sidx[k], i1 = sidx[k + 1], i2 = sidx[k + 2], i3 = sidx[k + 3];
            a0 += (xt[i0 * 3] * w0 + xt[i0 * 3 + 1] * w1 + xt[i0 * 3 + 2] * w2) * dv[i0];
            a1 += (xt[i1 * 3] * w0 + xt[i1 * 3 + 1] * w1 + xt[i1 * 3 + 2] * w2) * dv[i1];
            a2 += (xt[i2 * 3] * w0 + xt[i2 * 3 + 1] * w1 + xt[i2 * 3 + 2] * w2) * dv[i2];
            a3 += (xt[i3 * 3] * w0 + xt[i3 * 3 + 1] * w1 + xt[i3 * 3 + 2] * w2) * dv[i3];
        }
        for (; k < cnt; ++k) {
            const int i0 = sidx[k];
            a0 += (xt[i0 * 3] * w0 + xt[i0 * 3 + 1] * w1 + xt[i0 * 3 + 2] * w2) * dv[i0];
        }
        outv = dv[j] * ((a0 + a1) + (a2 + a3)) + b1[f];
        outv = fmaxf(outv, 0.0f);
    }
    H16[(size_t)t * NN * HH + j * HH + f] = f2b(outv);
}

// ---------------------------------------------------------------------------
// C2: column aggregation from bf16 XW2 (fp32 accum), bf16 out (layer 2)
// ---------------------------------------------------------------------------
__global__ __launch_bounds__(128) void agg_kernel(
    const unsigned short* __restrict__ XW16, const float* __restrict__ MF,
    const float* __restrict__ DINV, const int* __restrict__ CNT,
    const unsigned short* __restrict__ IDX, const float* __restrict__ bias,
    unsigned short* __restrict__ OUT16, int do_relu)
{
    const int bid = blockIdx.x;
    const int t = bid / NN;
    const int j = bid - t * NN;
    const int f = threadIdx.x;

    __shared__ unsigned short sidx[DEGCAP];

    const float mfj = MF[t * NN + j];
    int cnt = 0;
    if (mfj != 0.0f) cnt = min(CNT[t * NN + j], DEGCAP);
    const unsigned short* lst = IDX + ((size_t)t * NN + j) * DEGCAP;
    if (f < cnt) sidx[f] = lst[f];
    __syncthreads();

    float outv = 0.0f;
    if (mfj != 0.0f) {
        const unsigned short* base = XW16 + (size_t)t * NN * HH;
        float a0 = b2f(base[j * HH + f]), a1 = 0.0f, a2 = 0.0f, a3 = 0.0f;
        float a4 = 0.0f, a5 = 0.0f, a6 = 0.0f, a7 = 0.0f;
        int k = 0;
        for (; k + 8 <= cnt; k += 8) {
            a0 += b2f(base[(int)sidx[k]     * HH + f]);
            a1 += b2f(base[(int)sidx[k + 1] * HH + f]);
            a2 += b2f(base[(int)sidx[k + 2] * HH + f]);
            a3 += b2f(base[(int)sidx[k + 3] * HH + f]);
            a4 += b2f(base[(int)sidx[k + 4] * HH + f]);
            a5 += b2f(base[(int)sidx[k + 5] * HH + f]);
            a6 += b2f(base[(int)sidx[k + 6] * HH + f]);
            a7 += b2f(base[(int)sidx[k + 7] * HH + f]);
        }
        for (; k + 2 <= cnt; k += 2) {
            a0 += b2f(base[(int)sidx[k]     * HH + f]);
            a1 += b2f(base[(int)sidx[k + 1] * HH + f]);
        }
        if (k < cnt) a2 += b2f(base[(int)sidx[k] * HH + f]);
        outv = DINV[t * NN + j] * (((a0 + a1) + (a2 + a3)) + ((a4 + a5) + (a6 + a7))) + bias[f];
        if (do_relu) outv = fmaxf(outv, 0.0f);
    }
    OUT16[(size_t)t * NN * HH + j * HH + f] = f2b(outv);
}

// ---------------------------------------------------------------------------
// D (MFMA): XW2 = (H @ W2) * dinv on flat [25600][128]
// ---------------------------------------------------------------------------
__global__ __launch_bounds__(256) void xw2_kernel(
    const unsigned short* __restrict__ H16, const float* __restrict__ W2,
    const float* __restrict__ DINV, unsigned short* __restrict__ XW16)
{
    __shared__ unsigned short sm[SMEM_X];
    const int r0 = blockIdx.x * 128;
    const int tid = threadIdx.x;
    const int lane = tid & 63;
    const int wid = tid >> 6;
    const int g = lane >> 4, c = lane & 15;
    const int nt0 = 2 * wid;

#pragma unroll
    for (int it = 0; it < 8; ++it) {
        const int idx = it * 256 + tid;
        const int row = idx >> 4, h8 = (idx & 15) * 8;
        *reinterpret_cast<short8*>(&sm[row * SROW + h8]) =
            *reinterpret_cast<const short8*>(&H16[(size_t)(r0 + row) * HH + h8]);
    }
#pragma unroll
    for (int it = 0; it < 16; ++it) {
        const int flat = it * 1024 + tid * 4;
        float4 w = *reinterpret_cast<const float4*>(W2 + flat);
        const int h = flat >> 7, f0 = flat & 127;
        sm[XW_WOFF + (f0 + 0) * SROW + h] = f2b(w.x);
        sm[XW_WOFF + (f0 + 1) * SROW + h] = f2b(w.y);
        sm[XW_WOFF + (f0 + 2) * SROW + h] = f2b(w.z);
        sm[XW_WOFF + (f0 + 3) * SROW + h] = f2b(w.w);
    }
    __syncthreads();

    f32x4 acc[8][2];
#pragma unroll
    for (int m = 0; m < 8; ++m)
#pragma unroll
        for (int i = 0; i < 2; ++i) acc[m][i] = (f32x4)(0.0f);

#pragma unroll
    for (int kb = 0; kb < 4; ++kb) {
        short8 bf[2];
#pragma unroll
        for (int i = 0; i < 2; ++i)
            bf[i] = *reinterpret_cast<const short8*>(
                &sm[XW_WOFF + (16 * (nt0 + i) + c) * SROW + kb * 32 + 8 * g]);
#pragma unroll
        for (int m = 0; m < 8; ++m) {
            short8 af = *reinterpret_cast<const short8*>(
                &sm[(16 * m + c) * SROW + kb * 32 + 8 * g]);
#pragma unroll
            for (int i = 0; i < 2; ++i)
                acc[m][i] = __builtin_amdgcn_mfma_f32_16x16x32_bf16(af, bf[i], acc[m][i], 0, 0, 0);
        }
    }

#pragma unroll
    for (int m = 0; m < 8; ++m)
#pragma unroll
        for (int r = 0; r < 4; ++r) {
            const int row = 16 * m + 4 * g + r;
            const float dv = DINV[r0 + row];
#pragma unroll
            for (int i = 0; i < 2; ++i)
                XW16[(size_t)(r0 + row) * HH + 16 * (nt0 + i) + c] = f2b(acc[m][i][r] * dv);
        }
}

// ---------------------------------------------------------------------------
// Kernel E (fused): per-node 7-GEMM chain + MHA (R15 structure, unchanged).
// ---------------------------------------------------------------------------
template<int MODE>
__device__ __forceinline__ void stage(
    unsigned short* __restrict__ sm, int in_off, int out_off,
    const float* __restrict__ W, const float* __restrict__ bias,
    float* __restrict__ gout)
{
    const int tid = threadIdx.x;
    const int lane = tid & 63;
    const int wid = tid >> 6;
    const int g = lane >> 4, c = lane & 15;
    const int nt0 = 2 * wid;

    const float bv0 = bias[16 * nt0 + c];
    const float bv1 = bias[16 * nt0 + 16 + c];

    short8 bf[2][4];
#pragma unroll
    for (int i = 0; i < 2; ++i) {
        const float* wr = W + (16 * (nt0 + i) + c) * HH + 8 * g;
#pragma unroll
        for (int kb = 0; kb < 4; ++kb) {
            float4 w0 = *reinterpret_cast<const float4*>(wr + kb * 32);
            float4 w1 = *reinterpret_cast<const float4*>(wr + kb * 32 + 4);
            bf[i][kb] = cvt2(w0, w1);
        }
    }

    f32x4 acc[4][2];
#pragma unroll
    for (int m = 0; m < 4; ++m)
#pragma unroll
        for (int i = 0; i < 2; ++i) acc[m][i] = (f32x4)(0.0f);

#pragma unroll
    for (int kb = 0; kb < 4; ++kb) {
        short8 af[4];
#pragma unroll
        for (int m = 0; m < 4; ++m)
            af[m] = *reinterpret_cast<const short8*>(
                &sm[in_off + (16 * m + c) * SROW + kb * 32 + 8 * g]);
#pragma unroll
        for (int m = 0; m < 4; ++m)
#pragma unroll
            for (int i = 0; i < 2; ++i)
                acc[m][i] = __builtin_amdgcn_mfma_f32_16x16x32_bf16(af[m], bf[i][kb], acc[m][i], 0, 0, 0);
    }
    block_sync();   // all reads of in_off done (in-place safe)

    constexpr float scale = 0.17677669529663687f;  // 1/sqrt(32)
#pragma unroll
    for (int m = 0; m < 4; ++m)
#pragma unroll
        for (int i = 0; i < 2; ++i)
#pragma unroll
            for (int r = 0; r < 4; ++r) {
                const int row = 16 * m + 4 * g + r;
                if (row >= TT) continue;
                float v = acc[m][i][r] + (i ? bv1 : bv0);
                if (MODE == 1) v *= scale;
                const int col = 16 * (nt0 + i) + c;
                if (MODE == 3)      gout[row * HH + col] = v;
                else if (MODE == 2) sm[out_off + col * VROW + row] = f2b(v);
                else                sm[out_off + row * SROW + col] = f2b(v);
            }
    block_sync();
}

__global__ __launch_bounds__(256) void node_attn_kernel(
    const unsigned short* __restrict__ EMB16,
    const float* __restrict__ Wq, const float* __restrict__ bq,
    const float* __restrict__ Wk, const float* __restrict__ bk,
    const float* __restrict__ Wv, const float* __restrict__ bv,
    const float* __restrict__ W_in, const float* __restrict__ b_in,
    const float* __restrict__ W_out, const float* __restrict__ b_out,
    float* __restrict__ out)
{
    __shared__ unsigned short sm[SMEM_NA];
    const int n = blockIdx.x;
    const int tid = threadIdx.x;
    const int lane = tid & 63;
    const int wid = tid >> 6;
    const int g = lane >> 4, c = lane & 15;

    // zero Svt tail: cols 50..55 each d-row + 16-elem pad past row 127
    for (int idx = tid; idx < HH * 6 + 16; idx += 256) {
        if (idx < HH * 6) {
            int d = idx / 6, cc = idx - d * 6;
            sm[SV_OFF + d * VROW + TT + cc] = 0;
        } else {
            sm[SV_OFF + HH * VROW + (idx - HH * 6)] = 0;
        }
    }

    // stage emb (bf16) into PQ region
    for (int idx = tid; idx < TT * (HH / 8); idx += 256) {
        int t = idx >> 4, h8 = (idx & 15) * 8;
        *reinterpret_cast<short8*>(&sm[PQ_OFF + t * SROW + h8]) =
            *reinterpret_cast<const short8*>(&EMB16[((size_t)t * NN + n) * HH + h8]);
    }
    block_sync();

    const size_t nHH = (size_t)n * HH * HH;
    const size_t n3HH = (size_t)n * 3 * HH * HH;

    stage<0>(sm, PQ_OFF, SQ_OFF, Wq + nHH, bq + (size_t)n * HH, nullptr);
    stage<0>(sm, PQ_OFF, SK_OFF, Wk + nHH, bk + (size_t)n * HH, nullptr);
    stage<0>(sm, PQ_OFF, SV_OFF, Wv + nHH, bv + (size_t)n * HH, nullptr);
    stage<1>(sm, SQ_OFF, SQ_OFF, W_in + n3HH,                b_in + (size_t)n * 3 * HH,          nullptr);
    stage<0>(sm, SK_OFF, SK_OFF, W_in + n3HH + HH * HH,      b_in + (size_t)n * 3 * HH + HH,     nullptr);
    stage<2>(sm, SV_OFF, SV_OFF, W_in + n3HH + 2 * HH * HH,  b_in + (size_t)n * 3 * HH + 2 * HH, nullptr);

    const int hd = wid;

    f32x4 sacc[4][4];
#pragma unroll
    for (int m = 0; m < 4; ++m)
#pragma unroll
        for (int j = 0; j < 4; ++j) sacc[m][j] = (f32x4)(0.0f);

    short8 aq[4], bk8[4];
#pragma unroll
    for (int m = 0; m < 4; ++m)
        aq[m] = *reinterpret_cast<const short8*>(&sm[SQ_OFF + (16 * m + c) * SROW + hd * 32 + 8 * g]);
#pragma unroll
    for (int j = 0; j < 4; ++j)
        bk8[j] = *reinterpret_cast<const short8*>(&sm[SK_OFF + (16 * j + c) * SROW + hd * 32 + 8 * g]);
#pragma unroll
    for (int m = 0; m < 4; ++m)
#pragma unroll
        for (int j = 0; j < 4; ++j)
            sacc[m][j] = __builtin_amdgcn_mfma_f32_16x16x32_bf16(aq[m], bk8[j], sacc[m][j], 0, 0, 0);

    const bool mask3 = (c >= 2);
    unsigned short* Pbase = &sm[PQ_OFF + hd * 64 * PROW];
#pragma unroll
    for (int m = 0; m < 4; ++m)
#pragma unroll
        for (int r = 0; r < 4; ++r) {
            float v0 = sacc[m][0][r], v1 = sacc[m][1][r], v2 = sacc[m][2][r];
            float v3 = mask3 ? -3.0e38f : sacc[m][3][r];
            float mx = fmaxf(fmaxf(v0, v1), fmaxf(v2, v3));
            mx = fmaxf(mx, __shfl_xor(mx, 1, 16));
            mx = fmaxf(mx, __shfl_xor(mx, 2, 16));
            mx = fmaxf(mx, __shfl_xor(mx, 4, 16));
            mx = fmaxf(mx, __shfl_xor(mx, 8, 16));
            float e0 = __expf(v0 - mx), e1 = __expf(v1 - mx), e2 = __expf(v2 - mx);
            float e3 = mask3 ? 0.0f : __expf(v3 - mx);
            float sum_ = e0 + e1 + e2 + e3;
            sum_ += __shfl_xor(sum_, 1, 16);
            sum_ += __shfl_xor(sum_, 2, 16);
            sum_ += __shfl_xor(sum_, 4, 16);
            sum_ += __shfl_xor(sum_, 8, 16);
            float inv = 1.0f / sum_;
            const int q = 16 * m + 4 * g + r;
            unsigned short* pr = Pbase + q * PROW;
            pr[c]      = f2b(e0 * inv);
            pr[16 + c] = f2b(e1 * inv);
            pr[32 + c] = f2b(e2 * inv);
            pr[48 + c] = f2b(e3 * inv);
        }
    block_sync();

    f32x4 pacc[2][4];
#pragma unroll
    for (int mtd = 0; mtd < 2; ++mtd)
#pragma unroll
        for (int ntq = 0; ntq < 4; ++ntq) pacc[mtd][ntq] = (f32x4)(0.0f);

#pragma unroll
    for (int kb = 0; kb < 2; ++kb) {
        short8 av[2], bp[4];
#pragma unroll
        for (int mtd = 0; mtd < 2; ++mtd)
            av[mtd] = *reinterpret_cast<const short8*>(&sm[SV_OFF + (hd * 32 + 16 * mtd + c) * VROW + kb * 32 + 8 * g]);
#pragma unroll
        for (int ntq = 0; ntq < 4; ++ntq)
            bp[ntq] = *reinterpret_cast<const short8*>(&sm[PQ_OFF + hd * 64 * PROW + (16 * ntq + c) * PROW + kb * 32 + 8 * g]);
#pragma unroll
        for (int mtd = 0; mtd < 2; ++mtd)
#pragma unroll
            for (int ntq = 0; ntq < 4; ++ntq)
                pacc[mtd][ntq] = __builtin_amdgcn_mfma_f32_16x16x32_bf16(av[mtd], bp[ntq], pacc[mtd][ntq], 0, 0, 0);
    }

#pragma unroll
    for (int mtd = 0; mtd < 2; ++mtd)
#pragma unroll
        for (int ntq = 0; ntq < 4; ++ntq)
#pragma unroll
            for (int r = 0; r < 4; ++r) {
                const int q = 16 * ntq + c;
                if (q < TT)
                    sm[SQ_OFF + q * SROW + hd * 32 + 16 * mtd + 4 * g + r] = f2b(pacc[mtd][ntq][r]);
            }
    block_sync();

    stage<3>(sm, SQ_OFF, 0, W_out + nHH, b_out + (size_t)n * HH, out + (size_t)n * TT * HH);
}

// ---------------------------------------------------------------------------
extern "C" void kernel_launch(void* const* d_in, const int* in_sizes, int n_in,
                              void* d_out, int out_size, void* d_ws, size_t ws_size,
                              hipStream_t stream)
{
    const float* x     = (const float*)d_in[0];
    const float* adj   = (const float*)d_in[1];
    const int*   ego   = (const int*)d_in[2];
    const float* W1    = (const float*)d_in[3];
    const float* b1    = (const float*)d_in[4];
    const float* W2    = (const float*)d_in[5];
    const float* b2    = (const float*)d_in[6];
    const float* Wq    = (const float*)d_in[7];
    const float* bq    = (const float*)d_in[8];
    const float* Wk    = (const float*)d_in[9];
    const float* bk    = (const float*)d_in[10];
    const float* Wv    = (const float*)d_in[11];
    const float* bv    = (const float*)d_in[12];
    const float* W_in  = (const float*)d_in[13];
    const float* b_in  = (const float*)d_in[14];
    const float* W_out = (const float*)d_in[15];
    const float* b_out = (const float*)d_in[16];
    float* out = (float*)d_out;

    char* ws = (char*)d_ws;
    float*          MF    = (float*)(ws + 0);
    float*          DINV  = (float*)(ws + 102400);
    int*            CNT   = (int*)(ws + 204800);
    unsigned short* IDX   = (unsigned short*)(ws + 307200);     // 6,553,600
    unsigned short* XW16  = (unsigned short*)(ws + 6860800);    // 6,553,600
    unsigned short* H16   = (unsigned short*)(ws + 13414400);   // 6,553,600
    unsigned short* EMB16 = (unsigned short*)(ws + 19968000);   // 6,553,600

    mf_kernel<<<dim3(100), dim3(256), 0, stream>>>(ego, MF, CNT);
    edge_kernel<<<dim3(TT * 32), dim3(256), 0, stream>>>(adj, MF, CNT, IDX);
    dinv_kernel<<<dim3(100), dim3(256), 0, stream>>>(MF, CNT, DINV);
    agg1_kernel<<<dim3(TT * NN), dim3(128), 0, stream>>>(x, W1, MF, DINV, CNT, IDX, b1, H16);
    xw2_kernel<<<dim3(200), dim3(256), 0, stream>>>(H16, W2, DINV, XW16);
    agg_kernel<<<dim3(TT * NN), dim3(128), 0, stream>>>(XW16, MF, DINV, CNT, IDX, b2, EMB16, 0);
    node_attn_kernel<<<dim3(NN), dim3(256), 0, stream>>>(EMB16, Wq, bq, Wk, bk, Wv, bv,
                                                         W_in, b_in, W_out, b_out, out);
}